// Round 1
// baseline (548.141 us; speedup 1.0000x reference)
//
#include <hip/hip_runtime.h>
#include <math.h>

// Problem constants (fixed by reference)
#define BATCH 64
#define SEQL  512
#define DIN   256
#define NF    256
#define KS    3
#define KF    (KS * NF)   // 768

// ---------------------------------------------------------------------------
// Kernel 1: dynamic per-sample weights
//   W[b, d, kf] = sum_e U[d,e] * sigmoid(z[b,e]) * V[e,kf] + B_w[d,kf]
// Tiled GEMM: 64(d) x 64(kf) tile, e-chunks of 32, 256 threads, 4x4 microtile.
// ---------------------------------------------------------------------------
__global__ __launch_bounds__(256) void dyw_kernel(
    const float* __restrict__ z, const float* __restrict__ U,
    const float* __restrict__ V, const float* __restrict__ Bw,
    float* __restrict__ W)
{
    const int b   = blockIdx.z;
    const int d0  = blockIdx.x * 64;
    const int kf0 = blockIdx.y * 64;
    const int tid = threadIdx.x;
    const int ty  = tid >> 4;     // 0..15
    const int tx  = tid & 15;     // 0..15

    __shared__ float zf[DIN];
    __shared__ float As[32][64 + 1];  // [e_local][d_local]   (U^T tile)
    __shared__ float Bs[32][64 + 1];  // [e_local][kf_local]  (zf-scaled V tile)

    // sigmoid(z[b,:]) once per block (256 threads == DIN)
    {
        float zv = z[b * DIN + tid];
        zf[tid] = 1.0f / (1.0f + expf(-zv));
    }
    __syncthreads();

    float acc[4][4] = {};

    for (int e0 = 0; e0 < DIN; e0 += 32) {
        // U tile: rows d0..d0+63, cols e0..e0+31 -> As[e][d] (transposed store)
        #pragma unroll
        for (int it = 0; it < 8; ++it) {
            int idx = tid + it * 256;
            int dl  = idx >> 5;        // 0..63
            int el  = idx & 31;        // 0..31
            As[el][dl] = U[(d0 + dl) * DIN + (e0 + el)];
        }
        // V tile scaled by zf: rows e0..e0+31, cols kf0..kf0+63
        #pragma unroll
        for (int it = 0; it < 8; ++it) {
            int idx = tid + it * 256;
            int el  = idx >> 6;        // 0..31
            int kl  = idx & 63;        // 0..63
            Bs[el][kl] = V[(e0 + el) * KF + (kf0 + kl)] * zf[e0 + el];
        }
        __syncthreads();

        #pragma unroll
        for (int ee = 0; ee < 32; ++ee) {
            float a[4], bb[4];
            #pragma unroll
            for (int i = 0; i < 4; ++i) a[i] = As[ee][ty * 4 + i];
            #pragma unroll
            for (int j = 0; j < 4; ++j) bb[j] = Bs[ee][tx * 4 + j];
            #pragma unroll
            for (int i = 0; i < 4; ++i)
                #pragma unroll
                for (int j = 0; j < 4; ++j)
                    acc[i][j] = fmaf(a[i], bb[j], acc[i][j]);
        }
        __syncthreads();
    }

    // epilogue: add B_w, store W
    #pragma unroll
    for (int i = 0; i < 4; ++i) {
        int d = d0 + ty * 4 + i;
        #pragma unroll
        for (int j = 0; j < 4; ++j) {
            int kf = kf0 + tx * 4 + j;
            W[((size_t)b * DIN + d) * KF + kf] = acc[i][j] + Bw[d * KF + kf];
        }
    }
}

// ---------------------------------------------------------------------------
// Kernel 2: conv as GEMM over combined reduction dim kd = k*DIN + d (768)
//   out[b, l, f] = relu( sum_{k,d} x[b, l+k-1, d] * W[b, d, k*NF+f] + bias[f] )
// Tiled: 64(l) x 64(f), kd-chunks of 32 (each chunk has a single k).
// ---------------------------------------------------------------------------
__global__ __launch_bounds__(256) void conv_kernel(
    const float* __restrict__ x, const float* __restrict__ W,
    const float* __restrict__ bias, float* __restrict__ out)
{
    const int b   = blockIdx.z;
    const int l0  = blockIdx.x * 64;
    const int f0  = blockIdx.y * 64;
    const int tid = threadIdx.x;
    const int ty  = tid >> 4;
    const int tx  = tid & 15;

    __shared__ float Xs[32][64 + 1];  // [kd_local][l_local]
    __shared__ float Ws[32][64 + 1];  // [kd_local][f_local]

    float acc[4][4] = {};

    for (int c0 = 0; c0 < KS * DIN; c0 += 32) {
        const int k     = c0 / DIN;          // chunk lies in one k (256 % 32 == 0)
        const int dbase = c0 % DIN;

        // patch tile: Xs[cl][ll] = x[b, l0+ll+k-1, dbase+cl] (0 outside [0,SEQL))
        #pragma unroll
        for (int it = 0; it < 8; ++it) {
            int idx = tid + it * 256;
            int ll  = idx >> 5;       // 0..63
            int cl  = idx & 31;       // 0..31
            int l   = l0 + ll + k - 1;
            float v = 0.0f;
            if (l >= 0 && l < SEQL)
                v = x[((size_t)b * SEQL + l) * DIN + dbase + cl];
            Xs[cl][ll] = v;
        }
        // weight tile: Ws[cl][fl] = W[b, dbase+cl, k*NF + f0+fl]
        #pragma unroll
        for (int it = 0; it < 8; ++it) {
            int idx = tid + it * 256;
            int cl  = idx >> 6;       // 0..31
            int fl  = idx & 63;       // 0..63
            Ws[cl][fl] = W[((size_t)b * DIN + dbase + cl) * KF + k * NF + f0 + fl];
        }
        __syncthreads();

        #pragma unroll
        for (int ee = 0; ee < 32; ++ee) {
            float a[4], bb[4];
            #pragma unroll
            for (int i = 0; i < 4; ++i) a[i] = Xs[ee][ty * 4 + i];
            #pragma unroll
            for (int j = 0; j < 4; ++j) bb[j] = Ws[ee][tx * 4 + j];
            #pragma unroll
            for (int i = 0; i < 4; ++i)
                #pragma unroll
                for (int j = 0; j < 4; ++j)
                    acc[i][j] = fmaf(a[i], bb[j], acc[i][j]);
        }
        __syncthreads();
    }

    #pragma unroll
    for (int i = 0; i < 4; ++i) {
        int l = l0 + ty * 4 + i;
        #pragma unroll
        for (int j = 0; j < 4; ++j) {
            int f = f0 + tx * 4 + j;
            float v = acc[i][j] + bias[f];
            out[((size_t)b * SEQL + l) * NF + f] = fmaxf(v, 0.0f);
        }
    }
}

extern "C" void kernel_launch(void* const* d_in, const int* in_sizes, int n_in,
                              void* d_out, int out_size, void* d_ws, size_t ws_size,
                              hipStream_t stream) {
    const float* x    = (const float*)d_in[0];
    const float* z    = (const float*)d_in[1];
    const float* U    = (const float*)d_in[2];
    const float* V    = (const float*)d_in[3];
    const float* Bw   = (const float*)d_in[4];
    const float* bias = (const float*)d_in[5];
    // d_in[6] = kernel_size (always 3; compiled in)

    float* W   = (float*)d_ws;   // BATCH*DIN*KF*4 = 50.3 MB scratch
    float* out = (float*)d_out;

    dim3 blk(256);
    dim3 g1(DIN / 64, KF / 64, BATCH);     // 4 x 12 x 64 = 3072 blocks
    dyw_kernel<<<g1, blk, 0, stream>>>(z, U, V, Bw, W);

    dim3 g2(SEQL / 64, NF / 64, BATCH);    // 8 x 4 x 64 = 2048 blocks
    conv_kernel<<<g2, blk, 0, stream>>>(x, W, bias, out);
}

// Round 2
// 162.446 us; speedup vs baseline: 3.3743x; 3.3743x over previous
//
#include <hip/hip_runtime.h>
#include <math.h>

// Problem constants
#define BATCH 64
#define SEQL  512
#define DIN   256
#define NF    256
#define KS    3
#define KF    (KS * NF)        // 768

// Combined-channel formulation:
//   Xcat[b,l,ch] : ch<256 -> x[b,l,ch] ; ch>=256 -> Y[b,l,ch-256],
//   Y = (x @ U) * sigmoid(z)  (per-batch row scale)
//   out[b,l,f] = relu( sum_{k,ch} Xcat[b,l+k-1,ch] * Wc[k*512+ch, f] + bias[f] )
//   Wc[k*512+ch, f] = ch<256 ? B_w[ch, k*256+f] : V[ch-256, k*256+f]
#define XCH 512                 // combined channels
#define XL  (SEQL + 2)          // padded length (zeros at lp=0 and lp=513)
#define KC  (KS * XCH)          // 1536 combined reduction
#define LDT 40                  // LDS tile row stride in bf16 (32 + 8 pad)

typedef __attribute__((ext_vector_type(8))) short short8;
typedef __attribute__((ext_vector_type(4))) float floatx4;

static __device__ __forceinline__ unsigned short f2bf(float f) {
    unsigned int u = __float_as_uint(f);
    unsigned int r = (u + 0x7FFF + ((u >> 16) & 1)) >> 16;   // round-to-nearest-even
    return (unsigned short)r;
}

// ---------------------------------------------------------------------------
// pack_x: bf16-convert x into Xcat x-half; zero the l-pad rows (both halves).
// Grid (XL, BATCH) x 256 threads.
// ---------------------------------------------------------------------------
__global__ __launch_bounds__(256) void pack_x_kernel(
    const float* __restrict__ x, unsigned short* __restrict__ Xc)
{
    const int lp = blockIdx.x;       // 0..513
    const int b  = blockIdx.y;
    const int t  = threadIdx.x;      // 0..255
    const size_t o = ((size_t)b * XL + lp) * XCH;
    if (lp == 0 || lp == XL - 1) {
        ((unsigned int*)(Xc + o))[t] = 0u;     // 256 dwords = 512 bf16 zeros
    } else {
        Xc[o + t] = f2bf(x[((size_t)b * SEQL + (lp - 1)) * DIN + t]);
    }
}

// ---------------------------------------------------------------------------
// pack_w: build WcT[f][c] (c = k*512+ch) and UT[e][d], both bf16.
// Grid 256 blocks x 256 threads; blockIdx.x doubles as f and e.
// ---------------------------------------------------------------------------
__global__ __launch_bounds__(256) void pack_w_kernel(
    const float* __restrict__ U, const float* __restrict__ V,
    const float* __restrict__ Bw,
    unsigned short* __restrict__ WcT, unsigned short* __restrict__ UT)
{
    const int f = blockIdx.x;
    const int t = threadIdx.x;
    for (int c = t; c < KC; c += 256) {
        const int k  = c >> 9;
        const int ch = c & (XCH - 1);
        float v = (ch < DIN) ? Bw[(size_t)ch * KF + k * NF + f]
                             : V[(size_t)(ch - DIN) * KF + k * NF + f];
        WcT[(size_t)f * KC + c] = f2bf(v);
    }
    UT[(size_t)f * DIN + t] = f2bf(U[(size_t)t * DIN + f]);   // UT[e=f][d=t]
}

// ---------------------------------------------------------------------------
// stage1: Y[b,l,e] = (sum_d x[b,l,d] U[d,e]) * sigmoid(z[b,e]) -> Xcat Y-half.
// MFMA bf16 GEMM, M=B*L (reads bf16 x from Xcat), N=256, K=256.
// Grid (256, 2) x 256 threads. Block tile 128x128, BK=32.
// ---------------------------------------------------------------------------
__global__ __launch_bounds__(256) void stage1_kernel(
    unsigned short* __restrict__ Xc,          // read x-half, write Y-half
    const unsigned short* __restrict__ UT,    // [256 e][256 d]
    const float* __restrict__ z)
{
    __shared__ unsigned short As[128 * LDT];
    __shared__ unsigned short Bs[128 * LDT];

    const int tid  = threadIdx.x;
    const int lane = tid & 63;
    const int wave = tid >> 6;
    const int wm   = wave & 1, wn = wave >> 1;
    const int quad = lane >> 4;
    const int l16  = lane & 15;

    const int mt    = blockIdx.x;             // 0..255
    const int b     = mt >> 2;                // 4 m-tiles per batch row
    const int lbase = (mt & 3) * 128;
    const int e0    = blockIdx.y * 128;

    const int arow = tid >> 2;                // 0..63
    const int acol = (tid & 3) * 8;           // 0,8,16,24

    floatx4 acc[4][4] = {};

    for (int k0 = 0; k0 < DIN; k0 += 32) {
        // A tile: Xc[b][lbase+1+r][k0+acol] (x-half, bf16)
        const unsigned short* xb =
            Xc + ((size_t)b * XL + lbase + 1) * XCH + k0 + acol;
        #pragma unroll
        for (int it = 0; it < 2; ++it) {
            const int r = arow + it * 64;
            *(short8*)&As[r * LDT + acol] = *(const short8*)(xb + (size_t)r * XCH);
        }
        // B tile: UT[e0+fl][k0+acol]
        const unsigned short* ub = UT + (size_t)(e0 + arow) * DIN + k0 + acol;
        #pragma unroll
        for (int it = 0; it < 2; ++it) {
            *(short8*)&Bs[(arow + it * 64) * LDT + acol] =
                *(const short8*)(ub + (size_t)it * 64 * DIN);
        }
        __syncthreads();

        short8 af[4], bf[4];
        #pragma unroll
        for (int i = 0; i < 4; ++i)
            af[i] = *(const short8*)&As[(wm * 64 + i * 16 + l16) * LDT + quad * 8];
        #pragma unroll
        for (int j = 0; j < 4; ++j)
            bf[j] = *(const short8*)&Bs[(wn * 64 + j * 16 + l16) * LDT + quad * 8];
        #pragma unroll
        for (int i = 0; i < 4; ++i)
            #pragma unroll
            for (int j = 0; j < 4; ++j)
                acc[i][j] = __builtin_amdgcn_mfma_f32_16x16x32_bf16(
                    af[i], bf[j], acc[i][j], 0, 0, 0);
        __syncthreads();
    }

    // epilogue: scale by sigmoid(z[b,e]), write bf16 into Y-half (lp = l+1)
    #pragma unroll
    for (int j = 0; j < 4; ++j) {
        const int e  = e0 + wn * 64 + j * 16 + l16;
        const float zf = 1.0f / (1.0f + expf(-z[(size_t)b * DIN + e]));
        #pragma unroll
        for (int i = 0; i < 4; ++i) {
            const int lrow = lbase + wm * 64 + i * 16 + quad * 4;
            #pragma unroll
            for (int r = 0; r < 4; ++r) {
                const float v = acc[i][j][r] * zf;
                Xc[((size_t)b * XL + lrow + r + 1) * XCH + DIN + e] = f2bf(v);
            }
        }
    }
}

// ---------------------------------------------------------------------------
// stage2: out[b,l,f] = relu( sum_c A[m,c] WcT[f][c] + bias[f] )
//   A[m, k*512+ch] = Xcat[b, l+k-1, ch] = Xc[b][l+k][ch] (padded)
// Grid (256, 2) x 256 threads. Block tile 128x128, BK=32, K=1536.
// ---------------------------------------------------------------------------
__global__ __launch_bounds__(256) void stage2_kernel(
    const unsigned short* __restrict__ Xc,
    const unsigned short* __restrict__ WcT,   // [256 f][1536 c]
    const float* __restrict__ bias,
    float* __restrict__ out)
{
    __shared__ unsigned short As[128 * LDT];
    __shared__ unsigned short Bs[128 * LDT];

    const int tid  = threadIdx.x;
    const int lane = tid & 63;
    const int wave = tid >> 6;
    const int wm   = wave & 1, wn = wave >> 1;
    const int quad = lane >> 4;
    const int l16  = lane & 15;

    const int mt    = blockIdx.x;             // 0..255
    const int b     = mt >> 2;
    const int lbase = (mt & 3) * 128;
    const int f0    = blockIdx.y * 128;

    const int arow = tid >> 2;                // 0..63
    const int acol = (tid & 3) * 8;           // 0,8,16,24

    floatx4 acc[4][4] = {};

    for (int c0 = 0; c0 < KC; c0 += 32) {
        const int k  = c0 >> 9;               // conv tap (chunk within one k)
        const int ch = c0 & (XCH - 1);
        // A tile: Xc[b][lbase + r + k][ch + acol]
        const unsigned short* xb =
            Xc + ((size_t)b * XL + lbase + k) * XCH + ch + acol;
        #pragma unroll
        for (int it = 0; it < 2; ++it) {
            const int r = arow + it * 64;
            *(short8*)&As[r * LDT + acol] = *(const short8*)(xb + (size_t)r * XCH);
        }
        // B tile: WcT[f0+fl][c0+acol]
        const unsigned short* wb = WcT + (size_t)(f0 + arow) * KC + c0 + acol;
        #pragma unroll
        for (int it = 0; it < 2; ++it) {
            *(short8*)&Bs[(arow + it * 64) * LDT + acol] =
                *(const short8*)(wb + (size_t)it * 64 * KC);
        }
        __syncthreads();

        short8 af[4], bf[4];
        #pragma unroll
        for (int i = 0; i < 4; ++i)
            af[i] = *(const short8*)&As[(wm * 64 + i * 16 + l16) * LDT + quad * 8];
        #pragma unroll
        for (int j = 0; j < 4; ++j)
            bf[j] = *(const short8*)&Bs[(wn * 64 + j * 16 + l16) * LDT + quad * 8];
        #pragma unroll
        for (int i = 0; i < 4; ++i)
            #pragma unroll
            for (int j = 0; j < 4; ++j)
                acc[i][j] = __builtin_amdgcn_mfma_f32_16x16x32_bf16(
                    af[i], bf[j], acc[i][j], 0, 0, 0);
        __syncthreads();
    }

    #pragma unroll
    for (int j = 0; j < 4; ++j) {
        const int f  = f0 + wn * 64 + j * 16 + l16;
        const float bv = bias[f];
        #pragma unroll
        for (int i = 0; i < 4; ++i) {
            const int lrow = lbase + wm * 64 + i * 16 + quad * 4;
            #pragma unroll
            for (int r = 0; r < 4; ++r) {
                const float v = acc[i][j][r] + bv;
                out[((size_t)b * SEQL + lrow + r) * NF + f] = fmaxf(v, 0.0f);
            }
        }
    }
}

extern "C" void kernel_launch(void* const* d_in, const int* in_sizes, int n_in,
                              void* d_out, int out_size, void* d_ws, size_t ws_size,
                              hipStream_t stream) {
    const float* x    = (const float*)d_in[0];
    const float* z    = (const float*)d_in[1];
    const float* U    = (const float*)d_in[2];
    const float* V    = (const float*)d_in[3];
    const float* Bw   = (const float*)d_in[4];
    const float* bias = (const float*)d_in[5];

    // workspace layout (all 16B aligned)
    unsigned short* Xc  = (unsigned short*)d_ws;                    // 64*514*512*2 = 33,685,504 B
    unsigned short* WcT = Xc + (size_t)BATCH * XL * XCH;            // 256*1536*2   =    786,432 B
    unsigned short* UT  = WcT + (size_t)NF * KC;                    // 256*256*2    =    131,072 B
    float* out = (float*)d_out;

    pack_x_kernel<<<dim3(XL, BATCH), 256, 0, stream>>>(x, Xc);
    pack_w_kernel<<<dim3(256), 256, 0, stream>>>(U, V, Bw, WcT, UT);
    stage1_kernel<<<dim3(256, 2), 256, 0, stream>>>(Xc, UT, z);
    stage2_kernel<<<dim3(256, 2), 256, 0, stream>>>(Xc, WcT, bias, out);
}

// Round 3
// 160.906 us; speedup vs baseline: 3.4066x; 1.0096x over previous
//
#include <hip/hip_runtime.h>
#include <math.h>

// Problem constants
#define BATCH 64
#define SEQL  512
#define DIN   256
#define NF    256
#define KS    3
#define KF    (KS * NF)        // 768

// Combined-channel formulation:
//   Xcat[b,lp,ch] (lp = l+1, rows 0 and 513 are zero pad):
//     ch<256 -> bf16(x[b,l,ch]) ; ch>=256 -> Y[b,l,ch-256]
//   Y = (x @ U) * sigmoid(z)  (per-batch row scale)
//   out[b,l,f] = relu( sum_c Xc_flat[(b*XL+l)*XCH + c] * WcT[f][c] + bias[f] )
//     (c = k*512+ch, 0..1535 — im2col is a flat sliding window over Xc rows)
#define XCH 512
#define XL  (SEQL + 2)
#define KC  (KS * XCH)          // 1536

typedef __attribute__((ext_vector_type(8))) short short8;
typedef __attribute__((ext_vector_type(4))) float floatx4;
typedef __attribute__((ext_vector_type(4))) unsigned short ushort4v;

static __device__ __forceinline__ unsigned short f2bf(float f) {
    unsigned int u = __float_as_uint(f);
    return (unsigned short)((u + 0x7FFF + ((u >> 16) & 1)) >> 16);  // RTNE
}

// async 16B/lane global->LDS copy; lds dst is wave-uniform base + lane*16
static __device__ __forceinline__ void gl_lds16(const void* g, void* l) {
    __builtin_amdgcn_global_load_lds(
        (const __attribute__((address_space(1))) unsigned int*)g,
        (__attribute__((address_space(3))) unsigned int*)l, 16, 0, 0);
}

// ---------------------------------------------------------------------------
// pack: WcT[f][c] transpose-pack (96 blocks), UT[e][d] transpose (16 blocks),
//       zero Xc pad rows (64 blocks). 176 blocks x 256 threads.
// ---------------------------------------------------------------------------
__global__ __launch_bounds__(256) void pack_kernel(
    const float* __restrict__ U, const float* __restrict__ V,
    const float* __restrict__ Bw,
    unsigned short* __restrict__ WcT, unsigned short* __restrict__ UT,
    unsigned short* __restrict__ Xc)
{
    const int blk = blockIdx.x;
    const int t   = threadIdx.x;
    __shared__ unsigned short tile[64][64 + 2];

    if (blk < 96) {
        // WcT tile: f0 x c0, read coalesced in f, write coalesced in c
        const int f0 = (blk & 3) * 64, c0 = (blk >> 2) * 64;
        const int fl = t & 63, cb = t >> 6;
        #pragma unroll
        for (int it = 0; it < 16; ++it) {
            const int cl = cb + it * 4;
            const int c  = c0 + cl;
            const int k  = c >> 9, ch = c & (XCH - 1);
            const float v = (ch < DIN) ? Bw[(size_t)ch * KF + k * NF + f0 + fl]
                                       : V[(size_t)(ch - DIN) * KF + k * NF + f0 + fl];
            tile[cl][fl] = f2bf(v);
        }
        __syncthreads();
        const int cl2 = t & 63, fb = t >> 6;
        #pragma unroll
        for (int it = 0; it < 16; ++it) {
            const int fl2 = fb + it * 4;
            WcT[(size_t)(f0 + fl2) * KC + c0 + cl2] = tile[cl2][fl2];
        }
    } else if (blk < 112) {
        // UT[e][d] = bf16(U[d][e]) transpose
        const int bb = blk - 96;
        const int e0 = (bb & 3) * 64, d0 = (bb >> 2) * 64;
        const int el = t & 63, db = t >> 6;
        #pragma unroll
        for (int it = 0; it < 16; ++it) {
            const int dl = db + it * 4;
            tile[dl][el] = f2bf(U[(size_t)(d0 + dl) * DIN + e0 + el]);
        }
        __syncthreads();
        const int dl2 = t & 63, eb = t >> 6;
        #pragma unroll
        for (int it = 0; it < 16; ++it) {
            const int el2 = eb + it * 4;
            UT[(size_t)(e0 + el2) * DIN + d0 + dl2] = tile[dl2][el2];
        }
    } else {
        // zero both pad rows for batch b (512 bf16 = 256 dwords each)
        const int b = blk - 112;
        unsigned int* r0 = (unsigned int*)(Xc + (size_t)b * XL * XCH);
        unsigned int* r1 = (unsigned int*)(Xc + ((size_t)b * XL + XL - 1) * XCH);
        r0[t] = 0u;
        r1[t] = 0u;
    }
}

// ---------------------------------------------------------------------------
// stage1: Y = (x@U) * sigmoid(z) -> Xc Y-half; y==0 blocks also write bf16
// x-half. M-tile 128 rows, N-tile 128, BK=32, K=256. Grid (256,2) x 256.
// ---------------------------------------------------------------------------
__global__ __launch_bounds__(256) void stage1_kernel(
    const float* __restrict__ x, const unsigned short* __restrict__ UT,
    const float* __restrict__ z, unsigned short* __restrict__ Xc)
{
    __shared__ unsigned short As[128 * 32];
    __shared__ unsigned short Bs[128 * 32];

    const int tid  = threadIdx.x;
    const int lane = tid & 63;
    const int wave = tid >> 6;
    const int wm   = wave & 1, wn = wave >> 1;
    const int quad = lane >> 4, l16 = lane & 15;

    const int mt    = blockIdx.x;
    const int b     = mt >> 2;
    const int lbase = (mt & 3) * 128;
    const int e0    = blockIdx.y * 128;
    const bool writeX = (blockIdx.y == 0);

    // B staging (global_load_lds): wave covers rows wave*16..+15 (+64)
    const int srow = wave * 16 + (lane >> 2);
    const int scol = (lane & 3) * 8;            // ushort units (16 B)
    unsigned short* BsD0 = Bs + wave * 16 * 32;
    unsigned short* BsD1 = Bs + (64 + wave * 16) * 32;

    floatx4 acc[4][4] = {};

    for (int k0 = 0; k0 < DIN; k0 += 32) {
        const unsigned short* gB = UT + (size_t)(e0 + srow) * DIN + k0 + scol;
        gl_lds16(gB, BsD0);
        gl_lds16(gB + (size_t)64 * DIN, BsD1);

        // A staging: fp32 x -> bf16 LDS (+ Xc x-half from y==0)
        #pragma unroll
        for (int it = 0; it < 4; ++it) {
            const int idx = tid + it * 256;
            const int row = idx >> 3;
            const int col = (idx & 7) * 4;
            const float4 v = *(const float4*)(
                x + ((size_t)b * SEQL + lbase + row) * DIN + k0 + col);
            ushort4v h;
            h.x = f2bf(v.x); h.y = f2bf(v.y); h.z = f2bf(v.z); h.w = f2bf(v.w);
            *(ushort4v*)&As[row * 32 + col] = h;
            if (writeX)
                *(ushort4v*)&Xc[((size_t)b * XL + lbase + 1 + row) * XCH + k0 + col] = h;
        }
        __syncthreads();

        short8 af[4], bfr[4];
        #pragma unroll
        for (int i = 0; i < 4; ++i)
            af[i] = *(const short8*)&As[(wm * 64 + i * 16 + l16) * 32 + quad * 8];
        #pragma unroll
        for (int j = 0; j < 4; ++j)
            bfr[j] = *(const short8*)&Bs[(wn * 64 + j * 16 + l16) * 32 + quad * 8];
        #pragma unroll
        for (int i = 0; i < 4; ++i)
            #pragma unroll
            for (int j = 0; j < 4; ++j)
                acc[i][j] = __builtin_amdgcn_mfma_f32_16x16x32_bf16(
                    af[i], bfr[j], acc[i][j], 0, 0, 0);
        __syncthreads();
    }

    // epilogue: scale by sigmoid(z[b,e]), bf16 into Y-half (lp = l+1)
    #pragma unroll
    for (int j = 0; j < 4; ++j) {
        const int e = e0 + wn * 64 + j * 16 + l16;
        const float zf = 1.0f / (1.0f + expf(-z[(size_t)b * DIN + e]));
        #pragma unroll
        for (int i = 0; i < 4; ++i) {
            const int lrow = lbase + wm * 64 + i * 16 + quad * 4;
            #pragma unroll
            for (int r = 0; r < 4; ++r)
                Xc[((size_t)b * XL + lrow + r + 1) * XCH + DIN + e] =
                    f2bf(acc[i][j][r] * zf);
        }
    }
}

// ---------------------------------------------------------------------------
// stage2: out = relu(A @ WcT^T + bias). A is the flat sliding window over Xc.
// M-tile 128, N-tile 128, BK=32, K=1536. Grid (256,2) x 256.
// Staging addresses advance uniformly by 64 B per chunk (no tap logic).
// ---------------------------------------------------------------------------
__global__ __launch_bounds__(256) void stage2_kernel(
    const unsigned short* __restrict__ Xc,
    const unsigned short* __restrict__ WcT,
    const float* __restrict__ bias, float* __restrict__ out)
{
    __shared__ unsigned short As[128 * 32];
    __shared__ unsigned short Bs[128 * 32];

    const int tid  = threadIdx.x;
    const int lane = tid & 63;
    const int wave = tid >> 6;
    const int wm   = wave & 1, wn = wave >> 1;
    const int quad = lane >> 4, l16 = lane & 15;

    const int mt    = blockIdx.x;
    const int b     = mt >> 2;
    const int lbase = (mt & 3) * 128;
    const int f0    = blockIdx.y * 128;

    const int srow = wave * 16 + (lane >> 2);
    const int scol = (lane & 3) * 8;            // ushort units (16 B)
    const unsigned short* gA = Xc + ((size_t)b * XL + lbase + srow) * XCH + scol;
    const unsigned short* gB = WcT + (size_t)(f0 + srow) * KC + scol;
    unsigned short* AsD0 = As + wave * 16 * 32;
    unsigned short* AsD1 = As + (64 + wave * 16) * 32;
    unsigned short* BsD0 = Bs + wave * 16 * 32;
    unsigned short* BsD1 = Bs + (64 + wave * 16) * 32;

    floatx4 acc[4][4] = {};

    for (int c0 = 0; c0 < KC; c0 += 32) {
        gl_lds16(gA, AsD0);
        gl_lds16(gA + (size_t)64 * XCH, AsD1);
        gl_lds16(gB, BsD0);
        gl_lds16(gB + (size_t)64 * KC, BsD1);
        gA += 32;
        gB += 32;
        __syncthreads();

        short8 af[4], bfr[4];
        #pragma unroll
        for (int i = 0; i < 4; ++i)
            af[i] = *(const short8*)&As[(wm * 64 + i * 16 + l16) * 32 + quad * 8];
        #pragma unroll
        for (int j = 0; j < 4; ++j)
            bfr[j] = *(const short8*)&Bs[(wn * 64 + j * 16 + l16) * 32 + quad * 8];
        #pragma unroll
        for (int i = 0; i < 4; ++i)
            #pragma unroll
            for (int j = 0; j < 4; ++j)
                acc[i][j] = __builtin_amdgcn_mfma_f32_16x16x32_bf16(
                    af[i], bfr[j], acc[i][j], 0, 0, 0);
        __syncthreads();
    }

    #pragma unroll
    for (int j = 0; j < 4; ++j) {
        const int f  = f0 + wn * 64 + j * 16 + l16;
        const float bv = bias[f];
        #pragma unroll
        for (int i = 0; i < 4; ++i) {
            const int lrow = lbase + wm * 64 + i * 16 + quad * 4;
            #pragma unroll
            for (int r = 0; r < 4; ++r) {
                const float v = acc[i][j][r] + bv;
                out[((size_t)b * SEQL + lrow + r) * NF + f] = fmaxf(v, 0.0f);
            }
        }
    }
}

extern "C" void kernel_launch(void* const* d_in, const int* in_sizes, int n_in,
                              void* d_out, int out_size, void* d_ws, size_t ws_size,
                              hipStream_t stream) {
    const float* x    = (const float*)d_in[0];
    const float* z    = (const float*)d_in[1];
    const float* U    = (const float*)d_in[2];
    const float* V    = (const float*)d_in[3];
    const float* Bw   = (const float*)d_in[4];
    const float* bias = (const float*)d_in[5];

    unsigned short* Xc  = (unsigned short*)d_ws;          // 64*514*512*2 B
    unsigned short* WcT = Xc + (size_t)BATCH * XL * XCH;  // 256*1536*2 B
    unsigned short* UT  = WcT + (size_t)NF * KC;          // 256*256*2 B
    float* out = (float*)d_out;

    pack_kernel<<<dim3(176), 256, 0, stream>>>(U, V, Bw, WcT, UT, Xc);
    stage1_kernel<<<dim3(256, 2), 256, 0, stream>>>(x, UT, z, Xc);
    stage2_kernel<<<dim3(256, 2), 256, 0, stream>>>(Xc, WcT, bias, out);
}

// Round 4
// 148.884 us; speedup vs baseline: 3.6817x; 1.0807x over previous
//
#include <hip/hip_runtime.h>
#include <math.h>

// Problem constants
#define BATCH 64
#define SEQL  512
#define DIN   256
#define NF    256
#define KS    3
#define KF    (KS * NF)        // 768

// Combined-channel formulation:
//   Xcat[b,lp,ch] (lp = l+1, rows 0 and 513 zero):
//     ch<256 -> bf16(x[b,l,ch]) ; ch>=256 -> Y[b,l,ch-256] = (x@U)*sigmoid(z)
//   out[b,l,f] = relu( sum_c Xc_flat[(b*XL+l)*XCH + c] * WcT[f][c] + bias[f] )
//   (c = k*512+ch — im2col is a flat sliding window over Xc rows)
#define XCH 512
#define XL  (SEQL + 2)
#define KC  (KS * XCH)          // 1536
#define BK  64                  // K-chunk (2 MFMA sub-steps of 32)
#define LDR 64                  // LDS row stride in shorts (128 B), XOR-swizzled

typedef __attribute__((ext_vector_type(8))) short short8;
typedef __attribute__((ext_vector_type(4))) float floatx4;
typedef __attribute__((ext_vector_type(4))) unsigned short ushort4v;
typedef __attribute__((ext_vector_type(8))) unsigned short ushort8v;

static __device__ __forceinline__ unsigned short f2bf(float f) {
    unsigned int u = __float_as_uint(f);
    return (unsigned short)((u + 0x7FFF + ((u >> 16) & 1)) >> 16);  // RTNE
}

// async 16B/lane global->LDS; LDS dst = wave-uniform base + lane*16
static __device__ __forceinline__ void gl_lds16(const void* g, void* l) {
    __builtin_amdgcn_global_load_lds(
        (const __attribute__((address_space(1))) unsigned int*)g,
        (__attribute__((address_space(3))) unsigned int*)l, 16, 0, 0);
}

// ---------------------------------------------------------------------------
// pack: WcT[f][c] transpose (96 blk), UT[e][d] transpose (16 blk),
//       zero Xc pad rows (64 blk). 176 blocks x 256 threads.
// ---------------------------------------------------------------------------
__global__ __launch_bounds__(256) void pack_kernel(
    const float* __restrict__ U, const float* __restrict__ V,
    const float* __restrict__ Bw,
    unsigned short* __restrict__ WcT, unsigned short* __restrict__ UT,
    unsigned short* __restrict__ Xc)
{
    const int blk = blockIdx.x;
    const int t   = threadIdx.x;
    __shared__ unsigned short tile[64][64 + 2];

    if (blk < 96) {
        const int f0 = (blk & 3) * 64, c0 = (blk >> 2) * 64;
        const int fl = t & 63, cb = t >> 6;
        #pragma unroll
        for (int it = 0; it < 16; ++it) {
            const int cl = cb + it * 4;
            const int c  = c0 + cl;
            const int k  = c >> 9, ch = c & (XCH - 1);
            const float v = (ch < DIN) ? Bw[(size_t)ch * KF + k * NF + f0 + fl]
                                       : V[(size_t)(ch - DIN) * KF + k * NF + f0 + fl];
            tile[cl][fl] = f2bf(v);
        }
        __syncthreads();
        const int cl2 = t & 63, fb = t >> 6;
        #pragma unroll
        for (int it = 0; it < 16; ++it) {
            const int fl2 = fb + it * 4;
            WcT[(size_t)(f0 + fl2) * KC + c0 + cl2] = tile[cl2][fl2];
        }
    } else if (blk < 112) {
        const int bb = blk - 96;
        const int e0 = (bb & 3) * 64, d0 = (bb >> 2) * 64;
        const int el = t & 63, db = t >> 6;
        #pragma unroll
        for (int it = 0; it < 16; ++it) {
            const int dl = db + it * 4;
            tile[dl][el] = f2bf(U[(size_t)(d0 + dl) * DIN + e0 + el]);
        }
        __syncthreads();
        const int dl2 = t & 63, eb = t >> 6;
        #pragma unroll
        for (int it = 0; it < 16; ++it) {
            const int el2 = eb + it * 4;
            UT[(size_t)(e0 + el2) * DIN + d0 + dl2] = tile[dl2][el2];
        }
    } else {
        const int b = blk - 112;
        unsigned int* r0 = (unsigned int*)(Xc + (size_t)b * XL * XCH);
        unsigned int* r1 = (unsigned int*)(Xc + ((size_t)b * XL + XL - 1) * XCH);
        r0[t] = 0u;
        r1[t] = 0u;
    }
}

// ---------------------------------------------------------------------------
// stage1: Y = (x@U)*sigmoid(z) -> Xc Y-half; ft==0 blocks also write bf16
// x-half. 128x128 tile, BK=64, K=256. Grid 512 (mt,ft interleaved) x 256.
// LDS layout: [row][64] shorts, 16B units XOR-swizzled by (row&7).
// ---------------------------------------------------------------------------
__global__ __launch_bounds__(256) void stage1_kernel(
    const float* __restrict__ x, const unsigned short* __restrict__ UT,
    const float* __restrict__ z, unsigned short* __restrict__ Xc)
{
    __shared__ unsigned short As[128 * LDR];
    __shared__ unsigned short Bs[128 * LDR];

    const int tid  = threadIdx.x;
    const int lane = tid & 63;
    const int wave = tid >> 6;
    const int wm   = wave & 1, wn = wave >> 1;
    const int quad = lane >> 4, l16 = lane & 15;
    const int mx7  = l16 & 7;

    const int bid   = blockIdx.x;
    const int ft    = bid & 1;
    const int mt    = bid >> 1;
    const int b     = mt >> 2;
    const int lbase = (mt & 3) * 128;
    const int e0    = ft * 128;
    const bool writeX = (ft == 0);

    // B staging (gl_lds16): wave stages rows wave*32..+31, 4 calls x 8 rows
    const int r8  = lane >> 3;                 // 0..7 row within call
    const int ccd = lane & 7;                  // dst 16B unit
    const int ccg = ccd ^ r8;                  // swizzled global 16B unit
    unsigned short* BsW = Bs + (wave * 32) * LDR;

    floatx4 acc[4][4] = {};

    for (int k0 = 0; k0 < DIN; k0 += BK) {
        // B tile: Bs[n][cc'] = UT[e0+n][k0 + (cc'^(n&7))*8]
        #pragma unroll
        for (int t4 = 0; t4 < 4; ++t4) {
            const int row = wave * 32 + t4 * 8 + r8;
            gl_lds16(UT + (size_t)(e0 + row) * DIN + k0 + ccg * 8,
                     BsW + t4 * 8 * LDR);
        }
        // A tile: fp32 x -> bf16, swizzled store (+ Xc x-half when ft==0)
        #pragma unroll
        for (int it = 0; it < 4; ++it) {
            const int idx = tid + it * 256;
            const int row = idx >> 3;
            const int cd  = idx & 7;
            const int cg  = cd ^ (row & 7);
            const float* xp = x + ((size_t)b * SEQL + lbase + row) * DIN + k0 + cg * 8;
            const float4 v0 = *(const float4*)xp;
            const float4 v1 = *(const float4*)(xp + 4);
            ushort8v h;
            h[0] = f2bf(v0.x); h[1] = f2bf(v0.y); h[2] = f2bf(v0.z); h[3] = f2bf(v0.w);
            h[4] = f2bf(v1.x); h[5] = f2bf(v1.y); h[6] = f2bf(v1.z); h[7] = f2bf(v1.w);
            *(ushort8v*)&As[row * LDR + cd * 8] = h;
            if (writeX)
                *(ushort8v*)&Xc[((size_t)b * XL + lbase + 1 + row) * XCH + k0 + cg * 8] = h;
        }
        __syncthreads();

        #pragma unroll
        for (int ks8 = 0; ks8 < 8; ks8 += 4) {   // two K=32 sub-steps
            short8 af[4], bfr[4];
            #pragma unroll
            for (int i = 0; i < 4; ++i) {
                const int m = wm * 64 + i * 16 + l16;
                af[i] = *(const short8*)&As[m * LDR + (((ks8 + quad) ^ mx7) * 8)];
            }
            #pragma unroll
            for (int j = 0; j < 4; ++j) {
                const int n = wn * 64 + j * 16 + l16;
                bfr[j] = *(const short8*)&Bs[n * LDR + (((ks8 + quad) ^ mx7) * 8)];
            }
            #pragma unroll
            for (int i = 0; i < 4; ++i)
                #pragma unroll
                for (int j = 0; j < 4; ++j)
                    acc[i][j] = __builtin_amdgcn_mfma_f32_16x16x32_bf16(
                        af[i], bfr[j], acc[i][j], 0, 0, 0);
        }
        __syncthreads();
    }

    #pragma unroll
    for (int j = 0; j < 4; ++j) {
        const int e = e0 + wn * 64 + j * 16 + l16;
        const float zf = 1.0f / (1.0f + expf(-z[(size_t)b * DIN + e]));
        #pragma unroll
        for (int i = 0; i < 4; ++i) {
            const int lrow = lbase + wm * 64 + i * 16 + quad * 4;
            #pragma unroll
            for (int r = 0; r < 4; ++r)
                Xc[((size_t)b * XL + lrow + r + 1) * XCH + DIN + e] =
                    f2bf(acc[i][j][r] * zf);
        }
    }
}

// ---------------------------------------------------------------------------
// stage2: out = relu(A @ WcT^T + bias), A = flat sliding window over Xc.
// 128x128 tile, BK=64, K=1536 (24 barriers, 32 MFMA each). Grid 512 x 256.
// ---------------------------------------------------------------------------
__global__ __launch_bounds__(256) void stage2_kernel(
    const unsigned short* __restrict__ Xc,
    const unsigned short* __restrict__ WcT,
    const float* __restrict__ bias, float* __restrict__ out)
{
    __shared__ unsigned short As[128 * LDR];
    __shared__ unsigned short Bs[128 * LDR];

    const int tid  = threadIdx.x;
    const int lane = tid & 63;
    const int wave = tid >> 6;
    const int wm   = wave & 1, wn = wave >> 1;
    const int quad = lane >> 4, l16 = lane & 15;
    const int mx7  = l16 & 7;

    const int bid   = blockIdx.x;
    const int ft    = bid & 1;                 // f-tile pairs adjacent (share A)
    const int mt    = bid >> 1;
    const int b     = mt >> 2;
    const int lbase = (mt & 3) * 128;
    const int f0    = ft * 128;

    const int r8  = lane >> 3;
    const int ccd = lane & 7;
    const int ccg = ccd ^ r8;

    // per-lane global base addresses (advance 64 shorts per chunk)
    const unsigned short* gA =
        Xc + ((size_t)b * XL + lbase + wave * 32 + r8) * XCH + ccg * 8;
    const unsigned short* gB =
        WcT + (size_t)(f0 + wave * 32 + r8) * KC + ccg * 8;
    unsigned short* AsW = As + (wave * 32) * LDR;
    unsigned short* BsW = Bs + (wave * 32) * LDR;

    floatx4 acc[4][4] = {};

    for (int c0 = 0; c0 < KC; c0 += BK) {
        #pragma unroll
        for (int t4 = 0; t4 < 4; ++t4) {
            gl_lds16(gA + (size_t)(t4 * 8) * XCH, AsW + t4 * 8 * LDR);
            gl_lds16(gB + (size_t)(t4 * 8) * KC,  BsW + t4 * 8 * LDR);
        }
        gA += BK;
        gB += BK;
        __syncthreads();

        #pragma unroll
        for (int ks8 = 0; ks8 < 8; ks8 += 4) {
            short8 af[4], bfr[4];
            #pragma unroll
            for (int i = 0; i < 4; ++i) {
                const int m = wm * 64 + i * 16 + l16;
                af[i] = *(const short8*)&As[m * LDR + (((ks8 + quad) ^ mx7) * 8)];
            }
            #pragma unroll
            for (int j = 0; j < 4; ++j) {
                const int n = wn * 64 + j * 16 + l16;
                bfr[j] = *(const short8*)&Bs[n * LDR + (((ks8 + quad) ^ mx7) * 8)];
            }
            #pragma unroll
            for (int i = 0; i < 4; ++i)
                #pragma unroll
                for (int j = 0; j < 4; ++j)
                    acc[i][j] = __builtin_amdgcn_mfma_f32_16x16x32_bf16(
                        af[i], bfr[j], acc[i][j], 0, 0, 0);
        }
        __syncthreads();
    }

    #pragma unroll
    for (int j = 0; j < 4; ++j) {
        const int f  = f0 + wn * 64 + j * 16 + l16;
        const float bv = bias[f];
        #pragma unroll
        for (int i = 0; i < 4; ++i) {
            const int lrow = lbase + wm * 64 + i * 16 + quad * 4;
            #pragma unroll
            for (int r = 0; r < 4; ++r) {
                const float v = acc[i][j][r] + bv;
                out[((size_t)b * SEQL + lrow + r) * NF + f] = fmaxf(v, 0.0f);
            }
        }
    }
}

extern "C" void kernel_launch(void* const* d_in, const int* in_sizes, int n_in,
                              void* d_out, int out_size, void* d_ws, size_t ws_size,
                              hipStream_t stream) {
    const float* x    = (const float*)d_in[0];
    const float* z    = (const float*)d_in[1];
    const float* U    = (const float*)d_in[2];
    const float* V    = (const float*)d_in[3];
    const float* Bw   = (const float*)d_in[4];
    const float* bias = (const float*)d_in[5];

    unsigned short* Xc  = (unsigned short*)d_ws;          // 64*514*512*2 B
    unsigned short* WcT = Xc + (size_t)BATCH * XL * XCH;  // 256*1536*2 B
    unsigned short* UT  = WcT + (size_t)NF * KC;          // 256*256*2 B
    float* out = (float*)d_out;

    pack_kernel<<<dim3(176), 256, 0, stream>>>(U, V, Bw, WcT, UT, Xc);
    stage1_kernel<<<dim3(512), 256, 0, stream>>>(x, UT, z, Xc);
    stage2_kernel<<<dim3(512), 256, 0, stream>>>(Xc, WcT, bias, out);
}